// Round 18
// baseline (75.786 us; speedup 1.0000x reference)
//
#include <hip/hip_runtime.h>
#include <hip/hip_bf16.h>
#include <stdint.h>

typedef __attribute__((ext_vector_type(4))) float f32x4;
typedef __attribute__((ext_vector_type(4))) unsigned int u32x4;
typedef __attribute__((ext_vector_type(8))) int i32x8;

#define N_ROWS 8192
#define DIM 256            // K elements per row
#define ROWB 128           // bytes per row in fp4 (2 elems/byte)
#define BM 128             // i-rows per block (4 waves x 32 rows, t=2)
#define BJ 128             // j-cols staged per LDS tile (16 KB)
#define JCHUNKS 16
#define JCHUNK (N_ROWS / JCHUNKS)   // 512 -> 4 tiles of 128 per block

// r' = r_normalized * sqrt(10*log2(e)); dot(r'_i,r'_j) = 10*log2(e)*sim,
// so exp(10*sim) = exp2(dot).
#define SCL 3.79828252f

// E8M0 scale 2^-3 in all 4 bytes (127-3=124): data quantized as q=8*r',
// scale applied to BOTH A and B -> products x 2^-6 = exact /64.
#define SCALE_M3 0x7C7C7C7C

// e2m1 RTNE quantizer: grid {0,.5,1,1.5,2,3,4,6} x sign
__device__ __forceinline__ uint32_t q_e2m1(float y) {
  const uint32_t s = (__builtin_bit_cast(uint32_t, y) >> 31) << 3;
  const float a = fabsf(y);
  const uint32_t c = (a < 0.25f) ? 0u : (a < 0.75f) ? 1u : (a < 1.25f) ? 2u
                   : (a < 1.75f) ? 3u : (a < 2.5f)  ? 4u : (a < 3.5f)  ? 5u
                   : (a < 5.0f)  ? 6u : 7u;
  return s | c;
}

// ---- Kernel A: normalize rows -> fp4 e2m1 q=8*r'; zero den & out -----------
__global__ void k_norm(const float* __restrict__ reps,
                       unsigned char* __restrict__ rq,
                       float* __restrict__ den,
                       float* __restrict__ out) {
  const int w = threadIdx.x >> 6, lane = threadIdx.x & 63;
  const int row = blockIdx.x * 4 + w;
  const float4 v = reinterpret_cast<const float4*>(reps + row * DIM)[lane];
  float ss = v.x * v.x + v.y * v.y + v.z * v.z + v.w * v.w;
#pragma unroll
  for (int m = 1; m < 64; m <<= 1) ss += __shfl_xor(ss, m);
  const float qs = 8.0f * SCL / fmaxf(sqrtf(ss), 1e-12f);
  const uint32_t nib = q_e2m1(v.x * qs) | (q_e2m1(v.y * qs) << 4) |
                       (q_e2m1(v.z * qs) << 8) | (q_e2m1(v.w * qs) << 12);
  *reinterpret_cast<unsigned short*>(rq + (size_t)row * ROWB + lane * 2) =
      (unsigned short)nib;
  if (threadIdx.x < 4) den[blockIdx.x * 4 + threadIdx.x] = 0.0f;
  if (blockIdx.x == 0 && threadIdx.x == 0) out[0] = 0.0f;
}

// ---- Kernel B: MX-fp4 (16x16x128) fused sim + exp + mask + row-sum ---------
// R15's verified kernel with the grid doubled: (64,16) = 1024 blocks of
// 4 tiles each. Footprint (32 KB LDS, ~90 VGPR <= 128 cap) now gives
// 4 blocks/CU = 4 waves/SIMD (R15/R17 were grid-limited to 2 blocks/CU):
// four INDEPENDENT 4-wave blocks per CU overlap each other's barrier/drain
// idle, unlike R12's single-block 8-wave-coupled test.
__global__ __launch_bounds__(256, 2) void k_sim(
    const unsigned char* __restrict__ rq,
    const int* __restrict__ lab,
    float* __restrict__ den) {
  __shared__ unsigned char Bs[2][BJ * ROWB];  // 2 x 16 KB, 16B-chunk XOR-swizzled

  const int tid = threadIdx.x;
  const int w = tid >> 6, lane = tid & 63;
  const int l15 = lane & 15, lq = lane >> 4;
  const int ibase = blockIdx.x * BM + w * 32;   // this wave's 32 rows
  const int jc0 = blockIdx.y * JCHUNK;

  // A fragments: 2 i-subtiles x 2 K-windows; fp4 uses 16B/lane (4 VGPR) in
  // regs 0-3 of the v8i32 operand. Window kc = row bytes [kc*64+lq*16,+16).
  // Same map for A and B from the same matrix -> any k-permutation cancels.
  i32x8 a[2][2];
#pragma unroll
  for (int t = 0; t < 2; ++t) {
    const unsigned char* ap = rq + (size_t)(ibase + t * 16 + l15) * ROWB;
#pragma unroll
    for (int kc = 0; kc < 2; ++kc) {
      const u32x4 v0 = *reinterpret_cast<const u32x4*>(ap + kc * 64 + lq * 16);
      a[t][kc] = (i32x8){(int)v0.x, (int)v0.y, (int)v0.z, (int)v0.w, 0, 0, 0, 0};
    }
  }
  int labi[2][4];
#pragma unroll
  for (int t = 0; t < 2; ++t)
#pragma unroll
    for (int r = 0; r < 4; ++r)
      labi[t][r] = lab[ibase + t * 16 + lq * 4 + r];

  f32x4 dsum[2] = {{0.f, 0.f, 0.f, 0.f}, {0.f, 0.f, 0.f, 0.f}};

  const int lrow0 = w * 32;  // each wave stages 32 rows (4 instr x 8 rows)

  // prologue: stage tile 0 into buf 0 (16 KB: 4 instr x 4 waves x 1 KB)
#pragma unroll
  for (int q = 0; q < 4; ++q) {
    const int lrow = lrow0 + q * 8 + (lane >> 3);
    const int ch = (lane & 7) ^ (lrow & 7);  // 16B-chunk swizzle (8 chunks/row)
    const unsigned char* g = rq + (size_t)(jc0 + lrow) * ROWB + ch * 16;
    unsigned char* l = Bs[0] + (lrow0 + q * 8) * ROWB;  // +lane*16 implicit
    __builtin_amdgcn_global_load_lds(
        (const __attribute__((address_space(1))) uint32_t*)g,
        (__attribute__((address_space(3))) uint32_t*)l, 16, 0, 0);
  }

  for (int jt = 0; jt < JCHUNK / BJ; ++jt) {
    const int cur = jt & 1;
    const int j0 = jc0 + jt * BJ;

    __syncthreads();  // buf[cur] staged; prior reads of buf[cur^1] done

    // issue staging of NEXT tile into the other buffer (hidden under compute)
    if (jt < JCHUNK / BJ - 1) {
      const int jn = j0 + BJ;
#pragma unroll
      for (int q = 0; q < 4; ++q) {
        const int lrow = lrow0 + q * 8 + (lane >> 3);
        const int ch = (lane & 7) ^ (lrow & 7);
        const unsigned char* g = rq + (size_t)(jn + lrow) * ROWB + ch * 16;
        unsigned char* l = Bs[cur ^ 1] + (lrow0 + q * 8) * ROWB;
        __builtin_amdgcn_global_load_lds(
            (const __attribute__((address_space(1))) uint32_t*)g,
            (__attribute__((address_space(3))) uint32_t*)l, 16, 0, 0);
      }
    }

    int labj[8];
#pragma unroll
    for (int s = 0; s < 8; ++s) labj[s] = lab[j0 + s * 16 + l15];

    const unsigned char* Bb = Bs[cur];
#pragma unroll
    for (int s = 0; s < 8; ++s) {
      f32x4 acc0 = {0.f, 0.f, 0.f, 0.f};
      f32x4 acc1 = {0.f, 0.f, 0.f, 0.f};
      const int brow = s * 16 + l15;
      const unsigned char* bp = Bb + brow * ROWB;
      const int sw = brow & 7;
#pragma unroll
      for (int kc = 0; kc < 2; ++kc) {
        const int ch = (kc * 4 + lq) ^ sw;
        const u32x4 bv = *reinterpret_cast<const u32x4*>(bp + ch * 16);
        const i32x8 bb =
            (i32x8){(int)bv.x, (int)bv.y, (int)bv.z, (int)bv.w, 0, 0, 0, 0};
        // fmt codes: 4 = fp4 e2m1 for both A (cbsz) and B (blgp)
        acc0 = __builtin_amdgcn_mfma_scale_f32_16x16x128_f8f6f4(
            a[0][kc], bb, acc0, 4, 4, 0, SCALE_M3, 0, SCALE_M3);
        acc1 = __builtin_amdgcn_mfma_scale_f32_16x16x128_f8f6f4(
            a[1][kc], bb, acc1, 4, 4, 0, SCALE_M3, 0, SCALE_M3);
      }
#pragma unroll
      for (int r = 0; r < 4; ++r) {
        const float e0 = __builtin_amdgcn_exp2f(acc0[r]);
        const float e1 = __builtin_amdgcn_exp2f(acc1[r]);
        dsum[0][r] += (labi[0][r] == labj[s]) ? 1.0f : e0;
        dsum[1][r] += (labi[1][r] == labj[s]) ? 1.0f : e1;
      }
    }
  }

  // sum over the 16 lanes sharing each output row, then one atomic per row
#pragma unroll
  for (int t = 0; t < 2; ++t)
#pragma unroll
    for (int r = 0; r < 4; ++r) {
      float v = dsum[t][r];
      v += __shfl_xor(v, 1);
      v += __shfl_xor(v, 2);
      v += __shfl_xor(v, 4);
      v += __shfl_xor(v, 8);
      if (l15 == 0) atomicAdd(&den[ibase + t * 16 + lq * 4 + r], v);
    }
}

// ---- Kernel C: loss = mean(log(den + 1 + eps)) -----------------------------
__global__ void k_loss(const float* __restrict__ den, float* __restrict__ out) {
  const int idx = blockIdx.x * 256 + threadIdx.x;
  float v = logf(den[idx] + 1.0f + 1e-8f);  // +1 = num_diag
#pragma unroll
  for (int m = 1; m < 64; m <<= 1) v += __shfl_xor(v, m);
  __shared__ float sred[4];
  if ((threadIdx.x & 63) == 0) sred[threadIdx.x >> 6] = v;
  __syncthreads();
  if (threadIdx.x == 0)
    atomicAdd(out, (sred[0] + sred[1] + sred[2] + sred[3]) * (1.0f / (float)N_ROWS));
}

extern "C" void kernel_launch(void* const* d_in, const int* in_sizes, int n_in,
                              void* d_out, int out_size, void* d_ws, size_t ws_size,
                              hipStream_t stream) {
  const float* reps = (const float*)d_in[0];
  const int* lab = (const int*)d_in[1];
  float* out = (float*)d_out;
  unsigned char* rq = (unsigned char*)d_ws;                        // 1 MB fp4 q
  float* den = (float*)((char*)d_ws + (size_t)N_ROWS * ROWB);      // 32 KB

  k_norm<<<N_ROWS / 4, 256, 0, stream>>>(reps, rq, den, out);
  k_sim<<<dim3(N_ROWS / BM, JCHUNKS), 256, 0, stream>>>(rq, lab, den);
  k_loss<<<N_ROWS / 256, 256, 0, stream>>>(den, out);
}

// Round 19
// 30.055 us; speedup vs baseline: 2.5216x; 2.5216x over previous
//
#include <hip/hip_runtime.h>
#include <hip/hip_bf16.h>
#include <stdint.h>

typedef __attribute__((ext_vector_type(4))) float f32x4;
typedef __attribute__((ext_vector_type(4))) unsigned int u32x4;
typedef __attribute__((ext_vector_type(8))) int i32x8;

#define N_ROWS 8192
#define DIM 256            // K elements per row
#define ROWB 128           // bytes per row in fp4 (2 elems/byte)
#define BM 128             // i-rows per block (4 waves x 32 rows, t=2)
#define BJ 128             // j-cols staged per LDS tile (16 KB)
#define JCHUNKS 16
#define JCHUNK (N_ROWS / JCHUNKS)   // 512 -> 4 tiles of 128 per block

// r' = r_normalized * sqrt(10*log2(e)); dot(r'_i,r'_j) = 10*log2(e)*sim,
// so exp(10*sim) = exp2(dot).
#define SCL 3.79828252f

// E8M0 scale 2^-3 in all 4 bytes (127-3=124): data quantized as q=8*r',
// scale applied to BOTH A and B -> products x 2^-6 = exact /64.
#define SCALE_M3 0x7C7C7C7C

// e2m1 RTNE quantizer: grid {0,.5,1,1.5,2,3,4,6} x sign
__device__ __forceinline__ uint32_t q_e2m1(float y) {
  const uint32_t s = (__builtin_bit_cast(uint32_t, y) >> 31) << 3;
  const float a = fabsf(y);
  const uint32_t c = (a < 0.25f) ? 0u : (a < 0.75f) ? 1u : (a < 1.25f) ? 2u
                   : (a < 1.75f) ? 3u : (a < 2.5f)  ? 4u : (a < 3.5f)  ? 5u
                   : (a < 5.0f)  ? 6u : 7u;
  return s | c;
}

// ---- Kernel A: normalize rows -> fp4 e2m1 q=8*r'; zero den & out -----------
__global__ void k_norm(const float* __restrict__ reps,
                       unsigned char* __restrict__ rq,
                       float* __restrict__ den,
                       float* __restrict__ out) {
  const int w = threadIdx.x >> 6, lane = threadIdx.x & 63;
  const int row = blockIdx.x * 4 + w;
  const float4 v = reinterpret_cast<const float4*>(reps + row * DIM)[lane];
  float ss = v.x * v.x + v.y * v.y + v.z * v.z + v.w * v.w;
#pragma unroll
  for (int m = 1; m < 64; m <<= 1) ss += __shfl_xor(ss, m);
  const float qs = 8.0f * SCL / fmaxf(sqrtf(ss), 1e-12f);
  const uint32_t nib = q_e2m1(v.x * qs) | (q_e2m1(v.y * qs) << 4) |
                       (q_e2m1(v.z * qs) << 8) | (q_e2m1(v.w * qs) << 12);
  *reinterpret_cast<unsigned short*>(rq + (size_t)row * ROWB + lane * 2) =
      (unsigned short)nib;
  if (threadIdx.x < 4) den[blockIdx.x * 4 + threadIdx.x] = 0.0f;
  if (blockIdx.x == 0 && threadIdx.x == 0) out[0] = 0.0f;
}

// ---- Kernel B: MX-fp4 (16x16x128) fused sim + exp + mask + row-sum ---------
// R15's verified kernel, grid doubled to (64,16) = 1024 blocks (4 tiles
// each) for 4 blocks/CU = 4 waves/SIMD. R18's identical attempt SPILLED
// (VGPR=128-cap, 178 MB scratch): with only 4 jt trips the compiler fully
// unrolled the tile loop and cross-tile staging state blew past the cap.
// Fix: #pragma unroll 1 pins the jt loop rolled (one tile in flight),
// matching the liveness of the clean 8-trip R15 compile.
__global__ __launch_bounds__(256, 2) void k_sim(
    const unsigned char* __restrict__ rq,
    const int* __restrict__ lab,
    float* __restrict__ den) {
  __shared__ unsigned char Bs[2][BJ * ROWB];  // 2 x 16 KB, 16B-chunk XOR-swizzled

  const int tid = threadIdx.x;
  const int w = tid >> 6, lane = tid & 63;
  const int l15 = lane & 15, lq = lane >> 4;
  const int ibase = blockIdx.x * BM + w * 32;   // this wave's 32 rows
  const int jc0 = blockIdx.y * JCHUNK;

  // A fragments: 2 i-subtiles x 2 K-windows; fp4 uses 16B/lane (4 VGPR) in
  // regs 0-3 of the v8i32 operand. Window kc = row bytes [kc*64+lq*16,+16).
  // Same map for A and B from the same matrix -> any k-permutation cancels.
  i32x8 a[2][2];
#pragma unroll
  for (int t = 0; t < 2; ++t) {
    const unsigned char* ap = rq + (size_t)(ibase + t * 16 + l15) * ROWB;
#pragma unroll
    for (int kc = 0; kc < 2; ++kc) {
      const u32x4 v0 = *reinterpret_cast<const u32x4*>(ap + kc * 64 + lq * 16);
      a[t][kc] = (i32x8){(int)v0.x, (int)v0.y, (int)v0.z, (int)v0.w, 0, 0, 0, 0};
    }
  }
  int labi[2][4];
#pragma unroll
  for (int t = 0; t < 2; ++t)
#pragma unroll
    for (int r = 0; r < 4; ++r)
      labi[t][r] = lab[ibase + t * 16 + lq * 4 + r];

  f32x4 dsum[2] = {{0.f, 0.f, 0.f, 0.f}, {0.f, 0.f, 0.f, 0.f}};

  const int lrow0 = w * 32;  // each wave stages 32 rows (4 instr x 8 rows)

  // prologue: stage tile 0 into buf 0 (16 KB: 4 instr x 4 waves x 1 KB)
#pragma unroll
  for (int q = 0; q < 4; ++q) {
    const int lrow = lrow0 + q * 8 + (lane >> 3);
    const int ch = (lane & 7) ^ (lrow & 7);  // 16B-chunk swizzle (8 chunks/row)
    const unsigned char* g = rq + (size_t)(jc0 + lrow) * ROWB + ch * 16;
    unsigned char* l = Bs[0] + (lrow0 + q * 8) * ROWB;  // +lane*16 implicit
    __builtin_amdgcn_global_load_lds(
        (const __attribute__((address_space(1))) uint32_t*)g,
        (__attribute__((address_space(3))) uint32_t*)l, 16, 0, 0);
  }

#pragma unroll 1
  for (int jt = 0; jt < JCHUNK / BJ; ++jt) {
    const int cur = jt & 1;
    const int j0 = jc0 + jt * BJ;

    __syncthreads();  // buf[cur] staged; prior reads of buf[cur^1] done

    // issue staging of NEXT tile into the other buffer (hidden under compute)
    if (jt < JCHUNK / BJ - 1) {
      const int jn = j0 + BJ;
#pragma unroll
      for (int q = 0; q < 4; ++q) {
        const int lrow = lrow0 + q * 8 + (lane >> 3);
        const int ch = (lane & 7) ^ (lrow & 7);
        const unsigned char* g = rq + (size_t)(jn + lrow) * ROWB + ch * 16;
        unsigned char* l = Bs[cur ^ 1] + (lrow0 + q * 8) * ROWB;
        __builtin_amdgcn_global_load_lds(
            (const __attribute__((address_space(1))) uint32_t*)g,
            (__attribute__((address_space(3))) uint32_t*)l, 16, 0, 0);
      }
    }

    int labj[8];
#pragma unroll
    for (int s = 0; s < 8; ++s) labj[s] = lab[j0 + s * 16 + l15];

    const unsigned char* Bb = Bs[cur];
#pragma unroll
    for (int s = 0; s < 8; ++s) {
      f32x4 acc0 = {0.f, 0.f, 0.f, 0.f};
      f32x4 acc1 = {0.f, 0.f, 0.f, 0.f};
      const int brow = s * 16 + l15;
      const unsigned char* bp = Bb + brow * ROWB;
      const int sw = brow & 7;
#pragma unroll
      for (int kc = 0; kc < 2; ++kc) {
        const int ch = (kc * 4 + lq) ^ sw;
        const u32x4 bv = *reinterpret_cast<const u32x4*>(bp + ch * 16);
        const i32x8 bb =
            (i32x8){(int)bv.x, (int)bv.y, (int)bv.z, (int)bv.w, 0, 0, 0, 0};
        // fmt codes: 4 = fp4 e2m1 for both A (cbsz) and B (blgp)
        acc0 = __builtin_amdgcn_mfma_scale_f32_16x16x128_f8f6f4(
            a[0][kc], bb, acc0, 4, 4, 0, SCALE_M3, 0, SCALE_M3);
        acc1 = __builtin_amdgcn_mfma_scale_f32_16x16x128_f8f6f4(
            a[1][kc], bb, acc1, 4, 4, 0, SCALE_M3, 0, SCALE_M3);
      }
#pragma unroll
      for (int r = 0; r < 4; ++r) {
        const float e0 = __builtin_amdgcn_exp2f(acc0[r]);
        const float e1 = __builtin_amdgcn_exp2f(acc1[r]);
        dsum[0][r] += (labi[0][r] == labj[s]) ? 1.0f : e0;
        dsum[1][r] += (labi[1][r] == labj[s]) ? 1.0f : e1;
      }
    }
  }

  // sum over the 16 lanes sharing each output row, then one atomic per row
#pragma unroll
  for (int t = 0; t < 2; ++t)
#pragma unroll
    for (int r = 0; r < 4; ++r) {
      float v = dsum[t][r];
      v += __shfl_xor(v, 1);
      v += __shfl_xor(v, 2);
      v += __shfl_xor(v, 4);
      v += __shfl_xor(v, 8);
      if (l15 == 0) atomicAdd(&den[ibase + t * 16 + lq * 4 + r], v);
    }
}

// ---- Kernel C: loss = mean(log(den + 1 + eps)) -----------------------------
__global__ void k_loss(const float* __restrict__ den, float* __restrict__ out) {
  const int idx = blockIdx.x * 256 + threadIdx.x;
  float v = logf(den[idx] + 1.0f + 1e-8f);  // +1 = num_diag
#pragma unroll
  for (int m = 1; m < 64; m <<= 1) v += __shfl_xor(v, m);
  __shared__ float sred[4];
  if ((threadIdx.x & 63) == 0) sred[threadIdx.x >> 6] = v;
  __syncthreads();
  if (threadIdx.x == 0)
    atomicAdd(out, (sred[0] + sred[1] + sred[2] + sred[3]) * (1.0f / (float)N_ROWS));
}

extern "C" void kernel_launch(void* const* d_in, const int* in_sizes, int n_in,
                              void* d_out, int out_size, void* d_ws, size_t ws_size,
                              hipStream_t stream) {
  const float* reps = (const float*)d_in[0];
  const int* lab = (const int*)d_in[1];
  float* out = (float*)d_out;
  unsigned char* rq = (unsigned char*)d_ws;                        // 1 MB fp4 q
  float* den = (float*)((char*)d_ws + (size_t)N_ROWS * ROWB);      // 32 KB

  k_norm<<<N_ROWS / 4, 256, 0, stream>>>(reps, rq, den, out);
  k_sim<<<dim3(N_ROWS / BM, JCHUNKS), 256, 0, stream>>>(rq, lab, den);
  k_loss<<<N_ROWS / 256, 256, 0, stream>>>(den, out);
}

// Round 20
// 29.633 us; speedup vs baseline: 2.5575x; 1.0142x over previous
//
#include <hip/hip_runtime.h>
#include <hip/hip_bf16.h>
#include <stdint.h>

typedef __attribute__((ext_vector_type(4))) float f32x4;
typedef __attribute__((ext_vector_type(4))) unsigned int u32x4;
typedef __attribute__((ext_vector_type(8))) int i32x8;

#define N_ROWS 8192
#define DIM 256            // K elements per row
#define ROWB 128           // bytes per row in fp4 (2 elems/byte)
#define BM 128             // i-rows per block (4 waves x 32 rows, t=2)
#define BJ 256             // j-cols staged per LDS super-tile (32 KB)
#define JCHUNKS 8
#define JCHUNK (N_ROWS / JCHUNKS)   // 1024 -> 4 super-tiles of 256 per block

// r' = r_normalized * sqrt(10*log2(e)); dot(r'_i,r'_j) = 10*log2(e)*sim,
// so exp(10*sim) = exp2(dot).
#define SCL 3.79828252f

// E8M0 scale 2^-3 in all 4 bytes (127-3=124): data quantized as q=8*r',
// scale applied to BOTH A and B -> products x 2^-6 = exact /64.
#define SCALE_M3 0x7C7C7C7C

// e2m1 RTNE quantizer: grid {0,.5,1,1.5,2,3,4,6} x sign
__device__ __forceinline__ uint32_t q_e2m1(float y) {
  const uint32_t s = (__builtin_bit_cast(uint32_t, y) >> 31) << 3;
  const float a = fabsf(y);
  const uint32_t c = (a < 0.25f) ? 0u : (a < 0.75f) ? 1u : (a < 1.25f) ? 2u
                   : (a < 1.75f) ? 3u : (a < 2.5f)  ? 4u : (a < 3.5f)  ? 5u
                   : (a < 5.0f)  ? 6u : 7u;
  return s | c;
}

// ---- Kernel A: normalize rows -> fp4 e2m1 q=8*r'; zero den & out -----------
__global__ void k_norm(const float* __restrict__ reps,
                       unsigned char* __restrict__ rq,
                       float* __restrict__ den,
                       float* __restrict__ out) {
  const int w = threadIdx.x >> 6, lane = threadIdx.x & 63;
  const int row = blockIdx.x * 4 + w;
  const float4 v = reinterpret_cast<const float4*>(reps + row * DIM)[lane];
  float ss = v.x * v.x + v.y * v.y + v.z * v.z + v.w * v.w;
#pragma unroll
  for (int m = 1; m < 64; m <<= 1) ss += __shfl_xor(ss, m);
  const float qs = 8.0f * SCL / fmaxf(sqrtf(ss), 1e-12f);
  const uint32_t nib = q_e2m1(v.x * qs) | (q_e2m1(v.y * qs) << 4) |
                       (q_e2m1(v.z * qs) << 8) | (q_e2m1(v.w * qs) << 12);
  *reinterpret_cast<unsigned short*>(rq + (size_t)row * ROWB + lane * 2) =
      (unsigned short)nib;
  if (threadIdx.x < 4) den[blockIdx.x * 4 + threadIdx.x] = 0.0f;
  if (blockIdx.x == 0 && threadIdx.x == 0) out[0] = 0.0f;
}

// ---- Kernel B: MX-fp4 (16x16x128) fused sim + exp + mask + row-sum ---------
// Final configuration (R17): grid (64,8), 256 thr, BJ=256 super-tiles
// (2 x 32 KB dbuf -> 2 blocks/CU), one barrier per super-tile, prefetch
// into the other buffer. Best verified point: 29.6 us total; k_sim ~21 us
// ~= 2x the perfectly-overlapped {LDS 5.1, MFMA 4.7, VALU ~6} us floor —
// residual is 2-phase structure cost (R19 showed more TLP is neutral).
__global__ __launch_bounds__(256, 2) void k_sim(
    const unsigned char* __restrict__ rq,
    const int* __restrict__ lab,
    float* __restrict__ den) {
  __shared__ unsigned char Bs[2][BJ * ROWB];  // 2 x 32 KB, 16B-chunk XOR-swizzled

  const int tid = threadIdx.x;
  const int w = tid >> 6, lane = tid & 63;
  const int l15 = lane & 15, lq = lane >> 4;
  const int ibase = blockIdx.x * BM + w * 32;   // this wave's 32 rows
  const int jc0 = blockIdx.y * JCHUNK;

  // A fragments: 2 i-subtiles x 2 K-windows; fp4 uses 16B/lane (4 VGPR) in
  // regs 0-3 of the v8i32 operand. Window kc = row bytes [kc*64+lq*16,+16).
  // Same map for A and B from the same matrix -> any k-permutation cancels.
  i32x8 a[2][2];
#pragma unroll
  for (int t = 0; t < 2; ++t) {
    const unsigned char* ap = rq + (size_t)(ibase + t * 16 + l15) * ROWB;
#pragma unroll
    for (int kc = 0; kc < 2; ++kc) {
      const u32x4 v0 = *reinterpret_cast<const u32x4*>(ap + kc * 64 + lq * 16);
      a[t][kc] = (i32x8){(int)v0.x, (int)v0.y, (int)v0.z, (int)v0.w, 0, 0, 0, 0};
    }
  }
  int labi[2][4];
#pragma unroll
  for (int t = 0; t < 2; ++t)
#pragma unroll
    for (int r = 0; r < 4; ++r)
      labi[t][r] = lab[ibase + t * 16 + lq * 4 + r];

  f32x4 dsum[2] = {{0.f, 0.f, 0.f, 0.f}, {0.f, 0.f, 0.f, 0.f}};

  const int lrow0 = w * 64;  // each wave stages 64 rows (8 instr x 8 rows)

  // prologue: stage super-tile 0 into buf 0 (32 KB: 8 instr x 4 waves x 1 KB)
#pragma unroll
  for (int q = 0; q < 8; ++q) {
    const int lrow = lrow0 + q * 8 + (lane >> 3);
    const int ch = (lane & 7) ^ (lrow & 7);  // 16B-chunk swizzle (8 chunks/row)
    const unsigned char* g = rq + (size_t)(jc0 + lrow) * ROWB + ch * 16;
    unsigned char* l = Bs[0] + (lrow0 + q * 8) * ROWB;  // +lane*16 implicit
    __builtin_amdgcn_global_load_lds(
        (const __attribute__((address_space(1))) uint32_t*)g,
        (__attribute__((address_space(3))) uint32_t*)l, 16, 0, 0);
  }

  for (int jt = 0; jt < JCHUNK / BJ; ++jt) {
    const int cur = jt & 1;
    const int j0 = jc0 + jt * BJ;

    __syncthreads();  // buf[cur] staged; prior reads of buf[cur^1] done

    // issue staging of NEXT super-tile into the other buffer
    if (jt < JCHUNK / BJ - 1) {
      const int jn = j0 + BJ;
#pragma unroll
      for (int q = 0; q < 8; ++q) {
        const int lrow = lrow0 + q * 8 + (lane >> 3);
        const int ch = (lane & 7) ^ (lrow & 7);
        const unsigned char* g = rq + (size_t)(jn + lrow) * ROWB + ch * 16;
        unsigned char* l = Bs[cur ^ 1] + (lrow0 + q * 8) * ROWB;
        __builtin_amdgcn_global_load_lds(
            (const __attribute__((address_space(1))) uint32_t*)g,
            (__attribute__((address_space(3))) uint32_t*)l, 16, 0, 0);
      }
    }

    int labj[16];
#pragma unroll
    for (int s = 0; s < 16; ++s) labj[s] = lab[j0 + s * 16 + l15];

    const unsigned char* Bb = Bs[cur];
#pragma unroll
    for (int s = 0; s < 16; ++s) {
      f32x4 acc0 = {0.f, 0.f, 0.f, 0.f};
      f32x4 acc1 = {0.f, 0.f, 0.f, 0.f};
      const int brow = s * 16 + l15;
      const unsigned char* bp = Bb + brow * ROWB;
      const int sw = brow & 7;
#pragma unroll
      for (int kc = 0; kc < 2; ++kc) {
        const int ch = (kc * 4 + lq) ^ sw;
        const u32x4 bv = *reinterpret_cast<const u32x4*>(bp + ch * 16);
        const i32x8 bb =
            (i32x8){(int)bv.x, (int)bv.y, (int)bv.z, (int)bv.w, 0, 0, 0, 0};
        // fmt codes: 4 = fp4 e2m1 for both A (cbsz) and B (blgp)
        acc0 = __builtin_amdgcn_mfma_scale_f32_16x16x128_f8f6f4(
            a[0][kc], bb, acc0, 4, 4, 0, SCALE_M3, 0, SCALE_M3);
        acc1 = __builtin_amdgcn_mfma_scale_f32_16x16x128_f8f6f4(
            a[1][kc], bb, acc1, 4, 4, 0, SCALE_M3, 0, SCALE_M3);
      }
#pragma unroll
      for (int r = 0; r < 4; ++r) {
        const float e0 = __builtin_amdgcn_exp2f(acc0[r]);
        const float e1 = __builtin_amdgcn_exp2f(acc1[r]);
        dsum[0][r] += (labi[0][r] == labj[s]) ? 1.0f : e0;
        dsum[1][r] += (labi[1][r] == labj[s]) ? 1.0f : e1;
      }
    }
  }

  // sum over the 16 lanes sharing each output row, then one atomic per row
#pragma unroll
  for (int t = 0; t < 2; ++t)
#pragma unroll
    for (int r = 0; r < 4; ++r) {
      float v = dsum[t][r];
      v += __shfl_xor(v, 1);
      v += __shfl_xor(v, 2);
      v += __shfl_xor(v, 4);
      v += __shfl_xor(v, 8);
      if (l15 == 0) atomicAdd(&den[ibase + t * 16 + lq * 4 + r], v);
    }
}

// ---- Kernel C: loss = mean(log(den + 1 + eps)) -----------------------------
__global__ void k_loss(const float* __restrict__ den, float* __restrict__ out) {
  const int idx = blockIdx.x * 256 + threadIdx.x;
  float v = logf(den[idx] + 1.0f + 1e-8f);  // +1 = num_diag
#pragma unroll
  for (int m = 1; m < 64; m <<= 1) v += __shfl_xor(v, m);
  __shared__ float sred[4];
  if ((threadIdx.x & 63) == 0) sred[threadIdx.x >> 6] = v;
  __syncthreads();
  if (threadIdx.x == 0)
    atomicAdd(out, (sred[0] + sred[1] + sred[2] + sred[3]) * (1.0f / (float)N_ROWS));
}

extern "C" void kernel_launch(void* const* d_in, const int* in_sizes, int n_in,
                              void* d_out, int out_size, void* d_ws, size_t ws_size,
                              hipStream_t stream) {
  const float* reps = (const float*)d_in[0];
  const int* lab = (const int*)d_in[1];
  float* out = (float*)d_out;
  unsigned char* rq = (unsigned char*)d_ws;                        // 1 MB fp4 q
  float* den = (float*)((char*)d_ws + (size_t)N_ROWS * ROWB);      // 32 KB

  k_norm<<<N_ROWS / 4, 256, 0, stream>>>(reps, rq, den, out);
  k_sim<<<dim3(N_ROWS / BM, JCHUNKS), 256, 0, stream>>>(rq, lab, den);
  k_loss<<<N_ROWS / 256, 256, 0, stream>>>(den, out);
}